// Round 9
// baseline (463.280 us; speedup 1.0000x reference)
//
#include <hip/hip_runtime.h>

// dims: B=16 W=32 M=512 NH=64 HALF=32 K=8 H=8 LK=16 LOUT=2 NSP=10 GCIN=24
// rows = B*M = 8192. Reference dtypes fp32; bf16 internally for MFMA.
// SINGLE kernel, 512 blocks x 256 thr, 5 phases split by software grid
// barrier (device-scope atomics + fences). Residency guaranteed:
// __launch_bounds__(256,2) => >=2 blocks/CU => capacity >= 512 = grid.

typedef __attribute__((ext_vector_type(8))) short bf16x8;
typedef __attribute__((ext_vector_type(4))) float f32x4;
#define MFMA16 __builtin_amdgcn_mfma_f32_16x16x32_bf16

__device__ __forceinline__ unsigned short f2bf(float f) {
    unsigned u = __float_as_uint(f);
    u += 0x7fff + ((u >> 16) & 1);          // RNE
    return (unsigned short)(u >> 16);
}
__device__ __forceinline__ float bf2f(unsigned short h) {
    return __uint_as_float(((unsigned)h) << 16);
}
__device__ __forceinline__ float fast_tanh(float x) {
    float e = __expf(2.f * x);
    return 1.f - 2.f / (e + 1.f);
}

// grid barrier: after __syncthreads the compiler has drained vmcnt (store
// completion), thread0 publishes with a device-scope fence + atomic, spins
// on the counter, fence-acquires, then block-barrier again.
__device__ __forceinline__ void gbar(unsigned* bar, unsigned phase) {
    __syncthreads();
    if (threadIdx.x == 0) {
        __threadfence();
        atomicAdd(bar, 1u);
        unsigned tgt = phase * 512u;
        while (__hip_atomic_load(bar, __ATOMIC_ACQUIRE,
                                 __HIP_MEMORY_SCOPE_AGENT) < tgt)
            __builtin_amdgcn_s_sleep(2);
        __threadfence();
    }
    __syncthreads();
}

__global__ __launch_bounds__(256, 2) void mega_kernel(
    const float* __restrict__ x, const float* __restrict__ Wih,
    const float* __restrict__ Whh, const float* __restrict__ bih,
    const float* __restrict__ bhh, const float* __restrict__ W1,
    const float* __restrict__ W2, float* __restrict__ lh,
    float* __restrict__ e1, float* __restrict__ e2,
    const float* __restrict__ conv_w, const float* __restrict__ conv_b,
    const float* __restrict__ convl_w, const float* __restrict__ convl_b,
    const float* __restrict__ gc1_w, unsigned short* __restrict__ rgT,
    const float* __restrict__ Wb, unsigned short* __restrict__ WbT,
    float* __restrict__ nrmss,
    const float* __restrict__ b1p, const float* __restrict__ Vp,
    const float* __restrict__ bvp, unsigned short* __restrict__ amxb,
    const float* __restrict__ wbp, const float* __restrict__ adj,
    unsigned short* __restrict__ adjmix,
    const float* __restrict__ gc1_b, const float* __restrict__ gc2_w,
    float* __restrict__ h1g,
    const float* __restrict__ gc2_b,
    const float* __restrict__ out_w, const float* __restrict__ out_b,
    float* __restrict__ out, unsigned* __restrict__ bar)
{
    __shared__ __align__(16) char smem[23296];
    int blk = blockIdx.x, t = threadIdx.x;

    // ================= P0: rnn+e | conv+rg | WbT | zero nrmss =============
    if (blk < 256) {
        int wid = t >> 6, lane = t & 63;
        int rowblk = blk * 32;
        int b = rowblk >> 9, mb = rowblk & 511;
        float* xs = (float*)smem;                               // [32][32]
        unsigned short* hs = (unsigned short*)(smem + 4096);    // [2][16][72]
        float* rrs = (float*)(smem + 8704);                     // [32][25]

        for (int u = t; u < 1024; u += 256) {
            int tt = u >> 5, c = u & 31;
            xs[tt * 32 + c] = x[(b * 32 + tt) * 512 + mb + c];
        }
        for (int u = t; u < 2304; u += 256) hs[u] = 0;
        __syncthreads();

        if (wid < 2) {
            // RNN (waves 0,1; 16 series each)
            int l15 = lane & 15, quad = lane >> 4;
            int row0 = rowblk + wid * 16;
            unsigned short* hw0 = hs + wid * 1152;

            bf16x8 afr[4][2];
#pragma unroll
            for (int mt = 0; mt < 4; ++mt)
#pragma unroll
                for (int hf = 0; hf < 2; ++hf) {
                    const float* src = Whh + (16 * mt + l15) * 64 + 32 * hf + quad * 8;
                    union { bf16x8 v; unsigned short u[8]; } tmp;
#pragma unroll
                    for (int j = 0; j < 8; ++j) tmp.u[j] = f2bf(src[j]);
                    afr[mt][hf] = tmp.v;
                }
            bf16x8 wfr[2][2][2];
#pragma unroll
            for (int e = 0; e < 2; ++e)
#pragma unroll
                for (int nt = 0; nt < 2; ++nt)
#pragma unroll
                    for (int kf = 0; kf < 2; ++kf) {
                        const float* Wsrc = (e ? W2 : W1);
                        const float* src = Wsrc + (16 * nt + l15) * 64 + 32 * kf + quad * 8;
                        union { bf16x8 v; unsigned short u[8]; } tmp;
#pragma unroll
                        for (int j = 0; j < 8; ++j) tmp.u[j] = f2bf(src[j]);
                        wfr[e][nt][kf] = tmp.v;
                    }
            float wihv[4][4], bsv[4][4];
#pragma unroll
            for (int mt = 0; mt < 4; ++mt)
#pragma unroll
                for (int r = 0; r < 4; ++r) {
                    int n = 16 * mt + quad * 4 + r;
                    wihv[mt][r] = Wih[n];
                    bsv[mt][r]  = bih[n] + bhh[n];
                }

            float th[4][4];
            for (int tstep = 0; tstep < 32; ++tstep) {
                bf16x8 b0 = *(bf16x8*)(hw0 + l15 * 72 + quad * 8);
                bf16x8 b1 = *(bf16x8*)(hw0 + l15 * 72 + 32 + quad * 8);
                float xt = xs[tstep * 32 + wid * 16 + l15];
                f32x4 acc[4];
#pragma unroll
                for (int mt = 0; mt < 4; ++mt) {
                    f32x4 z = {0.f, 0.f, 0.f, 0.f};
                    acc[mt] = MFMA16(afr[mt][0], b0, z, 0, 0, 0);
                    acc[mt] = MFMA16(afr[mt][1], b1, acc[mt], 0, 0, 0);
                }
#pragma unroll
                for (int mt = 0; mt < 4; ++mt) {
                    ushort4 hwv;
#pragma unroll
                    for (int r = 0; r < 4; ++r)
                        th[mt][r] = fast_tanh(acc[mt][r] + xt * wihv[mt][r] + bsv[mt][r]);
                    hwv.x = f2bf(th[mt][0]); hwv.y = f2bf(th[mt][1]);
                    hwv.z = f2bf(th[mt][2]); hwv.w = f2bf(th[mt][3]);
                    *(ushort4*)(hw0 + l15 * 72 + 16 * mt + quad * 4) = hwv;
                }
            }
#pragma unroll
            for (int mt = 0; mt < 4; ++mt)
                *(float4*)(lh + (row0 + l15) * 64 + 16 * mt + quad * 4) =
                    make_float4(th[mt][0], th[mt][1], th[mt][2], th[mt][3]);

            bf16x8 a0 = *(bf16x8*)(hw0 + l15 * 72 + quad * 8);
            bf16x8 a1 = *(bf16x8*)(hw0 + l15 * 72 + 32 + quad * 8);
#pragma unroll
            for (int e = 0; e < 2; ++e) {
                float* dst = e ? e2 : e1;
#pragma unroll
                for (int nt = 0; nt < 2; ++nt) {
                    f32x4 z = {0.f, 0.f, 0.f, 0.f};
                    f32x4 ee = MFMA16(a0, wfr[e][nt][0], z, 0, 0, 0);
                    ee = MFMA16(a1, wfr[e][nt][1], ee, 0, 0, 0);
#pragma unroll
                    for (int r = 0; r < 4; ++r)
                        dst[(row0 + quad * 4 + r) * 32 + 16 * nt + l15] = ee[r];
                }
            }
        } else {
            // conv + rg (waves 2,3; 16 rows each)
            int wid2 = wid - 2;
#pragma unroll
            for (int rep = 0; rep < 2; ++rep) {
                int task = rep * 64 + lane;
                int rl = wid2 * 16 + (task >> 3);
                int k  = task & 7;
                float s = conv_b[k];
                for (int w = 0; w < 32; ++w) s += xs[w * 32 + rl] * conv_w[k * 32 + w];
                float l0 = convl_b[k], l1 = l0;
                for (int tt = 0; tt < 16; ++tt) {
                    float wv = convl_w[k * 16 + tt];
                    l0 += xs[(2 * tt) * 32 + rl] * wv;
                    l1 += xs[(2 * tt + 1) * 32 + rl] * wv;
                }
                rrs[rl * 25 + k * 3 + 0] = fmaxf(s, 0.f);
                rrs[rl * 25 + k * 3 + 1] = fmaxf(l0, 0.f);
                rrs[rl * 25 + k * 3 + 2] = fmaxf(l1, 0.f);
            }
            __builtin_amdgcn_wave_barrier();
            int rl = wid2 * 16 + (lane & 15);
            int nb = lane >> 4;
#pragma unroll
            for (int q = 0; q < 16; ++q) {
                int n = nb * 16 + q;
                float acc = 0.f;
#pragma unroll
                for (int c = 0; c < 24; ++c) acc += rrs[rl * 25 + c] * gc1_w[c * 64 + n];
                rgT[b * 32768 + n * 512 + mb + rl] = f2bf(acc);
            }
        }
    } else {
        // Wb transpose (256 tiles) + nrmss zero (first 32 blocks)
        int bid = blk - 256;
        int nb = (bid & 15) * 32, kb = (bid >> 4) * 32;
        float* tile = (float*)smem;             // [32][33]
        if (bid < 32) nrmss[bid * 256 + t] = 0.f;
        for (int u = t; u < 1024; u += 256) {
            int r = u >> 5, c = u & 31;
            tile[r * 33 + c] = Wb[(kb + r) * 512 + nb + c];
        }
        __syncthreads();
        for (int u = t; u < 1024; u += 256) {
            int r = u >> 5, c = u & 31;
            WbT[(nb + r) * 512 + kb + c] = f2bf(tile[c * 33 + r]);
        }
    }

    gbar(bar, 1);

    // ================= P1: amx (2 tiles/block) ============================
    for (int tid = blk; tid < 1024; tid += 512) {
        __syncthreads();
        int bb = tid >> 6;
        int i0 = ((tid >> 3) & 7) * 64, j0 = (tid & 7) * 64;
        float* e2s = (float*)smem;                  // [64][33]
        float* e1s = (float*)(smem + 8448);         // [64][33]
        float* Vs  = (float*)(smem + 16896);        // [32]
        float* red = (float*)(smem + 17024);        // [16][68]
        for (int u = t; u < 2048; u += 256) {
            int r = u >> 5, c = u & 31;
            e2s[r * 33 + c] = e2[(bb * 512 + i0 + r) * 32 + c];
            e1s[r * 33 + c] = e1[(bb * 512 + j0 + r) * 32 + c] + b1p[c];
        }
        if (t < 32) Vs[t] = Vp[t];
        __syncthreads();
        int ti = (t >> 4) * 4, tj = (t & 15) * 4;
        float acc[4][4] = {};
#pragma unroll
        for (int h = 0; h < 32; ++h) {
            float vv = Vs[h];
            float xi[4], yj[4], Exi[4], Eyj[4];
#pragma unroll
            for (int p = 0; p < 4; ++p) { xi[p] = e2s[(ti + p) * 33 + h]; Exi[p] = __expf(xi[p]); }
#pragma unroll
            for (int q = 0; q < 4; ++q) { yj[q] = e1s[(tj + q) * 33 + h]; Eyj[q] = __expf(yj[q]); }
#pragma unroll
            for (int p = 0; p < 4; ++p)
#pragma unroll
                for (int q = 0; q < 4; ++q) {
                    float v = xi[p] + yj[q];
                    float prod = Exi[p] * Eyj[q];
                    float el = v > 0.f ? v : prod - 1.f;
                    acc[p][q] += vv * el;
                }
        }
        float bv = bvp[0];
        float ss[4] = {0.f, 0.f, 0.f, 0.f};
#pragma unroll
        for (int p = 0; p < 4; ++p) {
            float v0 = acc[p][0] + bv, v1 = acc[p][1] + bv;
            float v2 = acc[p][2] + bv, v3 = acc[p][3] + bv;
            ushort4 o;
            o.x = f2bf(v0); o.y = f2bf(v1); o.z = f2bf(v2); o.w = f2bf(v3);
            *(ushort4*)(amxb + (bb * 512 + i0 + ti + p) * 512 + j0 + tj) = o;
            ss[0] += v0 * v0; ss[1] += v1 * v1; ss[2] += v2 * v2; ss[3] += v3 * v3;
        }
#pragma unroll
        for (int q = 0; q < 4; ++q) red[(t >> 4) * 68 + tj + q] = ss[q];
        __syncthreads();
        if (t < 64) {
            float s = 0.f;
#pragma unroll
            for (int g = 0; g < 16; ++g) s += red[g * 68 + t];
            atomicAdd(&nrmss[bb * 512 + j0 + t], s);
        }
    }

    gbar(bar, 2);

    // ================= P2: gemm_adjmix (2 tiles/block) ====================
    for (int tid = blk; tid < 1024; tid += 512) {
        __syncthreads();
        int bb = tid >> 6;
        int i0 = ((tid >> 3) & 7) * 64, j0 = (tid & 7) * 64;
        short* As = (short*)smem;                    // [64*72]
        short* Bs = (short*)(smem + 9216);           // [64*72]
        float* rn = (float*)(smem + 18432);          // [512]
        int w = t >> 6, lane = t & 63;
        int l15 = lane & 15, quad = lane >> 4;
        for (int u = t; u < 512; u += 256)
            rn[u] = 1.f / fmaxf(sqrtf(nrmss[bb * 512 + u]), 1e-12f);
        const unsigned short* Ag = amxb + bb * 262144;
        f32x4 acc[4] = {};
        for (int kk = 1; kk <= 8; ++kk) {
            int k0 = (j0 + 64 * kk) & 511;      // last iter: k0 == j0
            __syncthreads();
#pragma unroll
            for (int u0 = 0; u0 < 2; ++u0) {
                int u = t + u0 * 256;
                int i = u >> 3, o = u & 7;
                *(int4*)(Bs + i * 72 + o * 8) =
                    *(const int4*)(WbT + (j0 + i) * 512 + k0 + o * 8);
                union { int4 v; unsigned short us[8]; } ur;
                ur.v = *(const int4*)(Ag + (i0 + i) * 512 + k0 + o * 8);
                union { int4 v; unsigned short us[8]; } ow;
#pragma unroll
                for (int c = 0; c < 8; ++c)
                    ow.us[c] = f2bf(bf2f(ur.us[c]) * rn[k0 + o * 8 + c]);
                *(int4*)(As + i * 72 + o * 8) = ow.v;
            }
            __syncthreads();
            bf16x8 a0 = *(bf16x8*)(As + (16 * w + l15) * 72 + quad * 8);
            bf16x8 a1 = *(bf16x8*)(As + (16 * w + l15) * 72 + 32 + quad * 8);
#pragma unroll
            for (int nt = 0; nt < 4; ++nt) {
                bf16x8 b0 = *(bf16x8*)(Bs + (16 * nt + l15) * 72 + quad * 8);
                bf16x8 b1 = *(bf16x8*)(Bs + (16 * nt + l15) * 72 + 32 + quad * 8);
                acc[nt] = MFMA16(a0, b0, acc[nt], 0, 0, 0);
                acc[nt] = MFMA16(a1, b1, acc[nt], 0, 0, 0);
            }
        }
        float wb = wbp[0];
#pragma unroll
        for (int nt = 0; nt < 4; ++nt)
#pragma unroll
        for (int r = 0; r < 4; ++r) {
            int il = 16 * w + quad * 4 + r;
            int jl = 16 * nt + l15;
            int i = i0 + il, j = j0 + jl;
            float s  = acc[nt][r] + wb;
            float cv = 1.f / (1.f + __expf(-s));
            float am = bf2f((unsigned short)As[il * 72 + jl]);
            float ad = adj[i * 512 + j];
            adjmix[(bb * 512 + i) * 512 + j] = f2bf(ad * cv + am * (1.f - cv));
        }
    }

    gbar(bar, 3);

    // ================= P3: gemm_h1 + h1g (blocks < 256) ===================
    if (blk < 256) {
        int bb = blk >> 4;
        int i0 = (blk & 15) * 32;
        short* As  = (short*)smem;                   // [32*72]
        short* Bs  = (short*)(smem + 4608);          // [64*72]
        float* h1s = (float*)(smem + 13824);         // [32][72]
        int w = t >> 6, lane = t & 63;
        int l15 = lane & 15, quad = lane >> 4;
        int rt = w & 1, ntb = (w >> 1) * 2;
        const unsigned short* Ag = adjmix + bb * 262144;
        const unsigned short* Bg = rgT + bb * 32768;
        f32x4 acc[2] = {};
        for (int k0 = 0; k0 < 512; k0 += 64) {
            __syncthreads();
            {
                int i = t >> 3, o = t & 7;
                *(int4*)(As + i * 72 + o * 8) =
                    *(const int4*)(Ag + (i0 + i) * 512 + k0 + o * 8);
            }
#pragma unroll
            for (int u0 = 0; u0 < 2; ++u0) {
                int u = t + u0 * 256;
                int i = u >> 3, o = u & 7;
                *(int4*)(Bs + i * 72 + o * 8) =
                    *(const int4*)(Bg + i * 512 + k0 + o * 8);
            }
            __syncthreads();
            bf16x8 a0 = *(bf16x8*)(As + (16 * rt + l15) * 72 + quad * 8);
            bf16x8 a1 = *(bf16x8*)(As + (16 * rt + l15) * 72 + 32 + quad * 8);
#pragma unroll
            for (int q = 0; q < 2; ++q) {
                int nt = ntb + q;
                bf16x8 b0 = *(bf16x8*)(Bs + (16 * nt + l15) * 72 + quad * 8);
                bf16x8 b1 = *(bf16x8*)(Bs + (16 * nt + l15) * 72 + 32 + quad * 8);
                acc[q] = MFMA16(a0, b0, acc[q], 0, 0, 0);
                acc[q] = MFMA16(a1, b1, acc[q], 0, 0, 0);
            }
        }
#pragma unroll
        for (int q = 0; q < 2; ++q)
#pragma unroll
        for (int r = 0; r < 4; ++r) {
            int il = 16 * rt + quad * 4 + r;
            int j = 16 * (ntb + q) + l15;
            h1s[il * 72 + j] = fmaxf(acc[q][r] + gc1_b[j], 0.f);
        }
        __syncthreads();
        for (int u = t; u < 320; u += 256) {
            int row = u / 10, ns = u - row * 10;
            float a2 = 0.f;
#pragma unroll
            for (int j = 0; j < 64; ++j) a2 += h1s[row * 72 + j] * gc2_w[j * 10 + ns];
            h1g[(bb * 512 + i0 + row) * 10 + ns] = a2;
        }
    }

    gbar(bar, 4);

    // ================= P4: ospout (16 rows/block) =========================
    {
        int r0 = blk * 16;
        int bb = r0 >> 9;
        int wid = t >> 6, lane = t & 63;
        float* Bsm = (float*)smem;                   // [10][512]
        float* ow  = (float*)(smem + 20480);         // [8][80]
        float* ob  = (float*)(smem + 23040);         // [8]
        float* g2b = (float*)(smem + 23072);         // [10]
        for (int u = t; u < 5120; u += 256) {
            int k = u / 10, ns = u - k * 10;
            Bsm[ns * 512 + k] = h1g[bb * 5120 + u];
        }
        if (t < 8)  ob[t]  = out_b[t];
        if (t < 10) g2b[t] = gc2_b[t];
        for (int u = t; u < 592; u += 256) {
            int hh = u / 74, c = u - hh * 74;
            ow[hh * 80 + c] = out_w[u];
        }
        __syncthreads();
#pragma unroll
        for (int half = 0; half < 4; ++half) {
            int row = r0 + half * 4 + wid, m = row & 511;
            const unsigned short* Ar = adjmix + row * 512;
            float a[8];
#pragma unroll
            for (int q = 0; q < 8; ++q) a[q] = bf2f(Ar[lane + 64 * q]);
            float os[10];
#pragma unroll
            for (int ns = 0; ns < 10; ++ns) {
                float s = 0.f;
#pragma unroll
                for (int q = 0; q < 8; ++q) s += a[q] * Bsm[ns * 512 + lane + 64 * q];
#pragma unroll
                for (int off = 32; off; off >>= 1) s += __shfl_xor(s, off);
                os[ns] = fmaxf(s + g2b[ns], 0.f);
            }
            float lv = lh[row * 64 + lane];
#pragma unroll
            for (int hh = 0; hh < 8; ++hh) {
                float t1 = lv * ow[hh * 80 + 10 + lane];
#pragma unroll
                for (int off = 32; off; off >>= 1) t1 += __shfl_xor(t1, off);
                if (lane == hh) {
                    float acc = ob[hh] + t1;
#pragma unroll
                    for (int ns = 0; ns < 10; ++ns) acc += os[ns] * ow[hh * 80 + ns];
                    out[bb * 4096 + hh * 512 + m] = acc;
                }
            }
        }
    }
}

// ---------------- launch ---------------------------------------------------
extern "C" void kernel_launch(void* const* d_in, const int* in_sizes, int n_in,
                              void* d_out, int out_size, void* d_ws, size_t ws_size,
                              hipStream_t stream)
{
    const float* x       = (const float*)d_in[0];
    const float* adj     = (const float*)d_in[1];
    const float* Wih     = (const float*)d_in[2];
    const float* Whh     = (const float*)d_in[3];
    const float* bih     = (const float*)d_in[4];
    const float* bhh     = (const float*)d_in[5];
    const float* W1      = (const float*)d_in[6];
    const float* W2      = (const float*)d_in[7];
    const float* b1      = (const float*)d_in[8];
    const float* V       = (const float*)d_in[9];
    const float* bv      = (const float*)d_in[10];
    const float* Wb      = (const float*)d_in[11];
    const float* wb      = (const float*)d_in[12];
    const float* conv_w  = (const float*)d_in[13];
    const float* conv_b  = (const float*)d_in[14];
    const float* convl_w = (const float*)d_in[15];
    const float* convl_b = (const float*)d_in[16];
    const float* gc1_w   = (const float*)d_in[17];
    const float* gc1_b   = (const float*)d_in[18];
    const float* gc2_w   = (const float*)d_in[19];
    const float* gc2_b   = (const float*)d_in[20];
    const float* out_w   = (const float*)d_in[21];
    const float* out_b   = (const float*)d_in[22];

    float* ws    = (float*)d_ws;
    float* lh    = ws;                  // 524288
    float* e1    = lh + 524288;         // 262144
    float* e2    = e1 + 262144;         // 262144
    float* nrmss = e2 + 262144;         // 8192
    float* h1g   = nrmss + 8192;        // 81920
    unsigned short* amxb    = (unsigned short*)(h1g + 81920);  // 4194304
    unsigned short* adjmixb = amxb + 4194304;                  // 4194304
    unsigned short* WbT     = adjmixb + 4194304;               // 262144
    unsigned short* rgT     = WbT + 262144;                    // 524288
    unsigned* bar = (unsigned*)(rgT + 524288);

    hipMemsetAsync(bar, 0, 64, stream);
    mega_kernel<<<512, 256, 0, stream>>>(
        x, Wih, Whh, bih, bhh, W1, W2, lh, e1, e2,
        conv_w, conv_b, convl_w, convl_b, gc1_w, rgT, Wb, WbT, nrmss,
        b1, V, bv, amxb, wb, adj, adjmixb,
        gc1_b, gc2_w, h1g, gc2_b, out_w, out_b, (float*)d_out, bar);
}

// Round 10
// 207.945 us; speedup vs baseline: 2.2279x; 2.2279x over previous
//
#include <hip/hip_runtime.h>

// dims: B=16 W=32 M=512 NH=64 HALF=32 K=8 H=8 LK=16 LOUT=2 NSP=10 GCIN=24
// rows = B*M = 8192. Reference dtypes fp32; bf16 internally for MFMA.
// 5 dispatches: fused1(rnn+e+conv+rg | wbt | zero), amx, gemm_adjmix,
// gemm_h1(+h1g), ospout(+final proj).
// NOTE (R9): single-launch mega-kernel with software grid barriers was
// tried and regressed 206->463 us (worst-phase VGPR/LDS union killed
// occupancy; barrier spin cost >> 3.5us/launch). Keep separate dispatches.

typedef __attribute__((ext_vector_type(8))) short bf16x8;
typedef __attribute__((ext_vector_type(4))) float f32x4;
#define MFMA16 __builtin_amdgcn_mfma_f32_16x16x32_bf16

__device__ __forceinline__ unsigned short f2bf(float f) {
    unsigned u = __float_as_uint(f);
    u += 0x7fff + ((u >> 16) & 1);          // RNE
    return (unsigned short)(u >> 16);
}
__device__ __forceinline__ float bf2f(unsigned short h) {
    return __uint_as_float(((unsigned)h) << 16);
}
__device__ __forceinline__ float fast_tanh(float x) {
    float e = __expf(2.f * x);
    return 1.f - 2.f / (e + 1.f);
}

// ---------------- K1: fused1 ----------------------------------------------
// blocks [0,256): 32 series each. Waves 0-1: RNN via MFMA + e1/e2 epilogue
//                 (16 series/wave). Waves 2-3: conv+rg for the same 32 rows.
// blocks [256,512): Wb transpose->bf16
// blocks [512,544): zero nrmss
__global__ __launch_bounds__(256) void fused1_kernel(
    const float* __restrict__ x, const float* __restrict__ Wih,
    const float* __restrict__ Whh, const float* __restrict__ bih,
    const float* __restrict__ bhh, const float* __restrict__ W1,
    const float* __restrict__ W2, float* __restrict__ lh,
    float* __restrict__ e1, float* __restrict__ e2,
    const float* __restrict__ conv_w, const float* __restrict__ conv_b,
    const float* __restrict__ convl_w, const float* __restrict__ convl_b,
    const float* __restrict__ gc1_w, unsigned short* __restrict__ rgT,
    const float* __restrict__ Wb, unsigned short* __restrict__ WbT,
    float* __restrict__ nrmss)
{
    __shared__ __align__(16) char smem[12160];
    int blk = blockIdx.x, t = threadIdx.x;

    if (blk < 256) {
        int wid = t >> 6, lane = t & 63;
        int rowblk = blk * 32;
        int b = rowblk >> 9, mb = rowblk & 511;
        float* xs = (float*)smem;                               // [32][32]
        unsigned short* hs = (unsigned short*)(smem + 4096);    // [2][16][72]
        float* rrs = (float*)(smem + 8704);                     // [32][25]

        for (int u = t; u < 1024; u += 256) {
            int tt = u >> 5, c = u & 31;
            xs[tt * 32 + c] = x[(b * 32 + tt) * 512 + mb + c];
        }
        for (int u = t; u < 2304; u += 256) hs[u] = 0;
        __syncthreads();

        if (wid < 2) {
            // RNN (waves 0,1; 16 series each)
            int l15 = lane & 15, quad = lane >> 4;
            int row0 = rowblk + wid * 16;
            unsigned short* hw0 = hs + wid * 1152;

            bf16x8 afr[4][2];
#pragma unroll
            for (int mt = 0; mt < 4; ++mt)
#pragma unroll
                for (int hf = 0; hf < 2; ++hf) {
                    const float* src = Whh + (16 * mt + l15) * 64 + 32 * hf + quad * 8;
                    union { bf16x8 v; unsigned short u[8]; } tmp;
#pragma unroll
                    for (int j = 0; j < 8; ++j) tmp.u[j] = f2bf(src[j]);
                    afr[mt][hf] = tmp.v;
                }
            bf16x8 wfr[2][2][2];
#pragma unroll
            for (int e = 0; e < 2; ++e)
#pragma unroll
                for (int nt = 0; nt < 2; ++nt)
#pragma unroll
                    for (int kf = 0; kf < 2; ++kf) {
                        const float* Wsrc = (e ? W2 : W1);
                        const float* src = Wsrc + (16 * nt + l15) * 64 + 32 * kf + quad * 8;
                        union { bf16x8 v; unsigned short u[8]; } tmp;
#pragma unroll
                        for (int j = 0; j < 8; ++j) tmp.u[j] = f2bf(src[j]);
                        wfr[e][nt][kf] = tmp.v;
                    }
            float wihv[4][4], bsv[4][4];
#pragma unroll
            for (int mt = 0; mt < 4; ++mt)
#pragma unroll
                for (int r = 0; r < 4; ++r) {
                    int n = 16 * mt + quad * 4 + r;
                    wihv[mt][r] = Wih[n];
                    bsv[mt][r]  = bih[n] + bhh[n];
                }

            float th[4][4];
            for (int tstep = 0; tstep < 32; ++tstep) {
                bf16x8 b0 = *(bf16x8*)(hw0 + l15 * 72 + quad * 8);
                bf16x8 b1 = *(bf16x8*)(hw0 + l15 * 72 + 32 + quad * 8);
                float xt = xs[tstep * 32 + wid * 16 + l15];
                f32x4 acc[4];
#pragma unroll
                for (int mt = 0; mt < 4; ++mt) {
                    f32x4 z = {0.f, 0.f, 0.f, 0.f};
                    acc[mt] = MFMA16(afr[mt][0], b0, z, 0, 0, 0);
                    acc[mt] = MFMA16(afr[mt][1], b1, acc[mt], 0, 0, 0);
                }
#pragma unroll
                for (int mt = 0; mt < 4; ++mt) {
                    ushort4 hwv;
#pragma unroll
                    for (int r = 0; r < 4; ++r)
                        th[mt][r] = fast_tanh(acc[mt][r] + xt * wihv[mt][r] + bsv[mt][r]);
                    hwv.x = f2bf(th[mt][0]); hwv.y = f2bf(th[mt][1]);
                    hwv.z = f2bf(th[mt][2]); hwv.w = f2bf(th[mt][3]);
                    *(ushort4*)(hw0 + l15 * 72 + 16 * mt + quad * 4) = hwv;
                }
            }
#pragma unroll
            for (int mt = 0; mt < 4; ++mt)
                *(float4*)(lh + (row0 + l15) * 64 + 16 * mt + quad * 4) =
                    make_float4(th[mt][0], th[mt][1], th[mt][2], th[mt][3]);

            bf16x8 a0 = *(bf16x8*)(hw0 + l15 * 72 + quad * 8);
            bf16x8 a1 = *(bf16x8*)(hw0 + l15 * 72 + 32 + quad * 8);
#pragma unroll
            for (int e = 0; e < 2; ++e) {
                float* dst = e ? e2 : e1;
#pragma unroll
                for (int nt = 0; nt < 2; ++nt) {
                    f32x4 z = {0.f, 0.f, 0.f, 0.f};
                    f32x4 ee = MFMA16(a0, wfr[e][nt][0], z, 0, 0, 0);
                    ee = MFMA16(a1, wfr[e][nt][1], ee, 0, 0, 0);
#pragma unroll
                    for (int r = 0; r < 4; ++r)
                        dst[(row0 + quad * 4 + r) * 32 + 16 * nt + l15] = ee[r];
                }
            }
        } else {
            // conv + rg (waves 2,3; 16 rows each)
            int wid2 = wid - 2;
#pragma unroll
            for (int rep = 0; rep < 2; ++rep) {
                int task = rep * 64 + lane;            // 128 tasks = 16 rows x 8 k
                int rl = wid2 * 16 + (task >> 3);
                int k  = task & 7;
                float s = conv_b[k];
                for (int w = 0; w < 32; ++w) s += xs[w * 32 + rl] * conv_w[k * 32 + w];
                float l0 = convl_b[k], l1 = l0;
                for (int tt = 0; tt < 16; ++tt) {
                    float wv = convl_w[k * 16 + tt];
                    l0 += xs[(2 * tt) * 32 + rl] * wv;
                    l1 += xs[(2 * tt + 1) * 32 + rl] * wv;
                }
                rrs[rl * 25 + k * 3 + 0] = fmaxf(s, 0.f);
                rrs[rl * 25 + k * 3 + 1] = fmaxf(l0, 0.f);
                rrs[rl * 25 + k * 3 + 2] = fmaxf(l1, 0.f);
            }
            __builtin_amdgcn_wave_barrier();
            int rl = wid2 * 16 + (lane & 15);
            int nb = lane >> 4;
#pragma unroll
            for (int q = 0; q < 16; ++q) {
                int n = nb * 16 + q;
                float acc = 0.f;
#pragma unroll
                for (int c = 0; c < 24; ++c) acc += rrs[rl * 25 + c] * gc1_w[c * 64 + n];
                rgT[b * 32768 + n * 512 + mb + rl] = f2bf(acc);
            }
        }
    } else if (blk < 512) {
        // Wb transpose
        int bid = blk - 256;
        int nb = (bid & 15) * 32, kb = (bid >> 4) * 32;
        float* tile = (float*)smem;             // [32][33]
        for (int u = t; u < 1024; u += 256) {
            int r = u >> 5, c = u & 31;
            tile[r * 33 + c] = Wb[(kb + r) * 512 + nb + c];
        }
        __syncthreads();
        for (int u = t; u < 1024; u += 256) {
            int r = u >> 5, c = u & 31;
            WbT[(nb + r) * 512 + kb + c] = f2bf(tile[c * 33 + r]);
        }
    } else {
        nrmss[(blk - 512) * 256 + t] = 0.f;
    }
}

// ---------------- K2: a_mx 4x4/thread, factorized exp, fused sumsq --------
__global__ __launch_bounds__(256) void amx_kernel(
    const float* __restrict__ e1, const float* __restrict__ e2,
    const float* __restrict__ b1p, const float* __restrict__ Vp,
    const float* __restrict__ bvp, unsigned short* __restrict__ amxb,
    float* __restrict__ nrmss)
{
    int bb = blockIdx.z;
    int i0 = blockIdx.y * 64, j0 = blockIdx.x * 64;
    __shared__ float e2s[64][33], e1s[64][33];
    __shared__ float Vs[32];
    __shared__ float red[16][68];
    int t = threadIdx.x;
    for (int u = t; u < 2048; u += 256) {
        int r = u >> 5, c = u & 31;
        e2s[r][c] = e2[(bb * 512 + i0 + r) * 32 + c];
        e1s[r][c] = e1[(bb * 512 + j0 + r) * 32 + c] + b1p[c];
    }
    if (t < 32) Vs[t] = Vp[t];
    __syncthreads();
    int ti = (t >> 4) * 4, tj = (t & 15) * 4;
    float acc[4][4] = {};
#pragma unroll
    for (int h = 0; h < 32; ++h) {
        float vv = Vs[h];
        float xi[4], yj[4], Exi[4], Eyj[4];
#pragma unroll
        for (int p = 0; p < 4; ++p) { xi[p] = e2s[ti + p][h]; Exi[p] = __expf(xi[p]); }
#pragma unroll
        for (int q = 0; q < 4; ++q) { yj[q] = e1s[tj + q][h]; Eyj[q] = __expf(yj[q]); }
#pragma unroll
        for (int p = 0; p < 4; ++p)
#pragma unroll
            for (int q = 0; q < 4; ++q) {
                float v = xi[p] + yj[q];
                float prod = Exi[p] * Eyj[q];
                float el = v > 0.f ? v : prod - 1.f;  // exp(xi+yj)=Exi*Eyj
                acc[p][q] += vv * el;
            }
    }
    float bv = bvp[0];
    float ss[4] = {0.f, 0.f, 0.f, 0.f};
#pragma unroll
    for (int p = 0; p < 4; ++p) {
        float v0 = acc[p][0] + bv, v1 = acc[p][1] + bv;
        float v2 = acc[p][2] + bv, v3 = acc[p][3] + bv;
        ushort4 o;
        o.x = f2bf(v0); o.y = f2bf(v1); o.z = f2bf(v2); o.w = f2bf(v3);
        *(ushort4*)(amxb + (bb * 512 + i0 + ti + p) * 512 + j0 + tj) = o;
        ss[0] += v0 * v0; ss[1] += v1 * v1; ss[2] += v2 * v2; ss[3] += v3 * v3;
    }
#pragma unroll
    for (int q = 0; q < 4; ++q) red[t >> 4][tj + q] = ss[q];
    __syncthreads();
    if (t < 64) {
        float s = 0.f;
#pragma unroll
        for (int g = 0; g < 16; ++g) s += red[g][t];
        atomicAdd(&nrmss[bb * 512 + j0 + t], s);
    }
}

// ---------------- K3: gemm_adjmix, wrap-ordered K so last A-tile == j0 ----
__global__ __launch_bounds__(256) void gemm_adjmix(
    const unsigned short* __restrict__ amxb, const unsigned short* __restrict__ WbT,
    const float* __restrict__ wbp, const float* __restrict__ adj,
    const float* __restrict__ nrmss, unsigned short* __restrict__ adjmix)
{
    int bb = blockIdx.z;
    int i0 = blockIdx.y * 64, j0 = blockIdx.x * 64;
    __shared__ __align__(16) short As[64 * 72];
    __shared__ __align__(16) short Bs[64 * 72];
    __shared__ float rn[512];
    int t = threadIdx.x, w = t >> 6, lane = t & 63;
    int l15 = lane & 15, quad = lane >> 4;
    for (int u = t; u < 512; u += 256)
        rn[u] = 1.f / fmaxf(sqrtf(nrmss[bb * 512 + u]), 1e-12f);
    const unsigned short* Ag = amxb + bb * 262144;
    f32x4 acc[4] = {};
    for (int kk = 1; kk <= 8; ++kk) {
        int k0 = (j0 + 64 * kk) & 511;      // last iter: k0 == j0
        __syncthreads();
#pragma unroll
        for (int u0 = 0; u0 < 2; ++u0) {
            int u = t + u0 * 256;
            int i = u >> 3, o = u & 7;
            *(int4*)(Bs + i * 72 + o * 8) =
                *(const int4*)(WbT + (j0 + i) * 512 + k0 + o * 8);
            union { int4 v; unsigned short us[8]; } ur;
            ur.v = *(const int4*)(Ag + (i0 + i) * 512 + k0 + o * 8);
            union { int4 v; unsigned short us[8]; } ow;
#pragma unroll
            for (int c = 0; c < 8; ++c)
                ow.us[c] = f2bf(bf2f(ur.us[c]) * rn[k0 + o * 8 + c]);
            *(int4*)(As + i * 72 + o * 8) = ow.v;
        }
        __syncthreads();
        bf16x8 a0 = *(bf16x8*)(As + (16 * w + l15) * 72 + quad * 8);
        bf16x8 a1 = *(bf16x8*)(As + (16 * w + l15) * 72 + 32 + quad * 8);
#pragma unroll
        for (int nt = 0; nt < 4; ++nt) {
            bf16x8 b0 = *(bf16x8*)(Bs + (16 * nt + l15) * 72 + quad * 8);
            bf16x8 b1 = *(bf16x8*)(Bs + (16 * nt + l15) * 72 + 32 + quad * 8);
            acc[nt] = MFMA16(a0, b0, acc[nt], 0, 0, 0);
            acc[nt] = MFMA16(a1, b1, acc[nt], 0, 0, 0);
        }
    }
    // As now holds scaled amx(i0:64, j0:64) in LDS
    float wb = wbp[0];
#pragma unroll
    for (int nt = 0; nt < 4; ++nt)
#pragma unroll
    for (int r = 0; r < 4; ++r) {
        int il = 16 * w + quad * 4 + r;
        int jl = 16 * nt + l15;
        int i = i0 + il, j = j0 + jl;
        float s  = acc[nt][r] + wb;
        float cv = 1.f / (1.f + __expf(-s));
        float am = bf2f((unsigned short)As[il * 72 + jl]);
        float ad = adj[i * 512 + j];
        adjmix[(bb * 512 + i) * 512 + j] = f2bf(ad * cv + am * (1.f - cv));
    }
}

// ---------------- K4: gemm_h1 + fused h1g = h1 @ gc2_w --------------------
__global__ __launch_bounds__(256) void gemm_h1(
    const unsigned short* __restrict__ adjmix, const unsigned short* __restrict__ rgT,
    const float* __restrict__ gc1_b, const float* __restrict__ gc2_w,
    float* __restrict__ h1g)
{
    int bb = blockIdx.y;
    int i0 = blockIdx.x * 32;
    __shared__ __align__(16) short As[32 * 72];
    __shared__ __align__(16) short Bs[64 * 72];
    __shared__ float h1s[32][72];
    int t = threadIdx.x, w = t >> 6, lane = t & 63;
    int l15 = lane & 15, quad = lane >> 4;
    int rt = w & 1, ntb = (w >> 1) * 2;
    const unsigned short* Ag = adjmix + bb * 262144;
    const unsigned short* Bg = rgT + bb * 32768;
    f32x4 acc[2] = {};
    for (int k0 = 0; k0 < 512; k0 += 64) {
        __syncthreads();
        {
            int i = t >> 3, o = t & 7;
            *(int4*)(As + i * 72 + o * 8) =
                *(const int4*)(Ag + (i0 + i) * 512 + k0 + o * 8);
        }
#pragma unroll
        for (int u0 = 0; u0 < 2; ++u0) {
            int u = t + u0 * 256;
            int i = u >> 3, o = u & 7;
            *(int4*)(Bs + i * 72 + o * 8) =
                *(const int4*)(Bg + i * 512 + k0 + o * 8);
        }
        __syncthreads();
        bf16x8 a0 = *(bf16x8*)(As + (16 * rt + l15) * 72 + quad * 8);
        bf16x8 a1 = *(bf16x8*)(As + (16 * rt + l15) * 72 + 32 + quad * 8);
#pragma unroll
        for (int q = 0; q < 2; ++q) {
            int nt = ntb + q;
            bf16x8 b0 = *(bf16x8*)(Bs + (16 * nt + l15) * 72 + quad * 8);
            bf16x8 b1 = *(bf16x8*)(Bs + (16 * nt + l15) * 72 + 32 + quad * 8);
            acc[q] = MFMA16(a0, b0, acc[q], 0, 0, 0);
            acc[q] = MFMA16(a1, b1, acc[q], 0, 0, 0);
        }
    }
#pragma unroll
    for (int q = 0; q < 2; ++q)
#pragma unroll
    for (int r = 0; r < 4; ++r) {
        int il = 16 * rt + quad * 4 + r;
        int j = 16 * (ntb + q) + l15;
        h1s[il][j] = fmaxf(acc[q][r] + gc1_b[j], 0.f);
    }
    __syncthreads();
    for (int u = t; u < 320; u += 256) {
        int row = u / 10, ns = u - row * 10;
        float a2 = 0.f;
#pragma unroll
        for (int j = 0; j < 64; ++j) a2 += h1s[row][j] * gc2_w[j * 10 + ns];
        h1g[(bb * 512 + i0 + row) * 10 + ns] = a2;
    }
}

// ---------------- K5: ospout, 16 rows/block -------------------------------
__global__ __launch_bounds__(256) void ospout_kernel(
    const unsigned short* __restrict__ adjmix, const float* __restrict__ h1g,
    const float* __restrict__ gc2_b, const float* __restrict__ lh,
    const float* __restrict__ out_w, const float* __restrict__ out_b,
    float* __restrict__ out)
{
    int r0 = blockIdx.x * 16;
    int bb = r0 >> 9;
    int wid = threadIdx.x >> 6, lane = threadIdx.x & 63;
    __shared__ float Bsm[10][512];
    __shared__ float ow[8][80];
    __shared__ float ob[8], g2b[10];
    for (int u = threadIdx.x; u < 5120; u += 256) {
        int k = u / 10, ns = u - k * 10;
        Bsm[ns][k] = h1g[bb * 5120 + u];
    }
    if (threadIdx.x < 8)  ob[threadIdx.x]  = out_b[threadIdx.x];
    if (threadIdx.x < 10) g2b[threadIdx.x] = gc2_b[threadIdx.x];
    for (int u = threadIdx.x; u < 592; u += 256) {
        int hh = u / 74, c = u - hh * 74;
        ow[hh][c] = out_w[u];
    }
    __syncthreads();
#pragma unroll
    for (int half = 0; half < 4; ++half) {
        int row = r0 + half * 4 + wid, m = row & 511;
        const unsigned short* Ar = adjmix + row * 512;
        float a[8];
#pragma unroll
        for (int q = 0; q < 8; ++q) a[q] = bf2f(Ar[lane + 64 * q]);
        float os[10];
#pragma unroll
        for (int ns = 0; ns < 10; ++ns) {
            float s = 0.f;
#pragma unroll
            for (int q = 0; q < 8; ++q) s += a[q] * Bsm[ns][lane + 64 * q];
#pragma unroll
            for (int off = 32; off; off >>= 1) s += __shfl_xor(s, off);
            os[ns] = fmaxf(s + g2b[ns], 0.f);
        }
        float lv = lh[row * 64 + lane];
#pragma unroll
        for (int hh = 0; hh < 8; ++hh) {
            float t1 = lv * ow[hh][10 + lane];
#pragma unroll
            for (int off = 32; off; off >>= 1) t1 += __shfl_xor(t1, off);
            if (lane == hh) {
                float acc = ob[hh] + t1;
#pragma unroll
                for (int ns = 0; ns < 10; ++ns) acc += os[ns] * ow[hh][ns];
                out[bb * 4096 + hh * 512 + m] = acc;
            }
        }
    }
}

// ---------------- launch ---------------------------------------------------
extern "C" void kernel_launch(void* const* d_in, const int* in_sizes, int n_in,
                              void* d_out, int out_size, void* d_ws, size_t ws_size,
                              hipStream_t stream)
{
    const float* x       = (const float*)d_in[0];
    const float* adj     = (const float*)d_in[1];
    const float* Wih     = (const float*)d_in[2];
    const float* Whh     = (const float*)d_in[3];
    const float* bih     = (const float*)d_in[4];
    const float* bhh     = (const float*)d_in[5];
    const float* W1      = (const float*)d_in[6];
    const float* W2      = (const float*)d_in[7];
    const float* b1      = (const float*)d_in[8];
    const float* V       = (const float*)d_in[9];
    const float* bv      = (const float*)d_in[10];
    const float* Wb      = (const float*)d_in[11];
    const float* wb      = (const float*)d_in[12];
    const float* conv_w  = (const float*)d_in[13];
    const float* conv_b  = (const float*)d_in[14];
    const float* convl_w = (const float*)d_in[15];
    const float* convl_b = (const float*)d_in[16];
    const float* gc1_w   = (const float*)d_in[17];
    const float* gc1_b   = (const float*)d_in[18];
    const float* gc2_w   = (const float*)d_in[19];
    const float* gc2_b   = (const float*)d_in[20];
    const float* out_w   = (const float*)d_in[21];
    const float* out_b   = (const float*)d_in[22];

    float* ws    = (float*)d_ws;
    float* lh    = ws;                  // 524288
    float* e1    = lh + 524288;         // 262144
    float* e2    = e1 + 262144;         // 262144
    float* nrmss = e2 + 262144;         // 8192
    float* h1g   = nrmss + 8192;        // 81920
    unsigned short* amxb    = (unsigned short*)(h1g + 81920);  // 4194304
    unsigned short* adjmixb = amxb + 4194304;                  // 4194304
    unsigned short* WbT     = adjmixb + 4194304;               // 262144
    unsigned short* rgT     = WbT + 262144;                    // 524288

    fused1_kernel<<<544, 256, 0, stream>>>(
        x, Wih, Whh, bih, bhh, W1, W2, lh, e1, e2,
        conv_w, conv_b, convl_w, convl_b, gc1_w, rgT, Wb, WbT, nrmss);
    amx_kernel<<<dim3(8, 8, 16), 256, 0, stream>>>(e1, e2, b1, V, bv,
                                                   amxb, nrmss);
    gemm_adjmix<<<dim3(8, 8, 16), 256, 0, stream>>>(amxb, WbT, wb, adj,
                                                    nrmss, adjmixb);
    gemm_h1<<<dim3(16, 16), 256, 0, stream>>>(adjmixb, rgT, gc1_b, gc2_w, h1g);
    ospout_kernel<<<512, 256, 0, stream>>>(adjmixb, h1g, gc2_b, lh,
                                           out_w, out_b, (float*)d_out);
}